// Round 3
// baseline (5797.672 us; speedup 1.0000x reference)
//
#include <hip/hip_runtime.h>

// CTRNN: T=512, B=256, I=64, H=256.
//   pre = x_t @ W_in^T + b_in + h @ W_hh^T + b_hh + noise_t
//   h   = max(0.8*h + 0.2*pre, 0)
//
// R3 structure:
//  Kernel 1 (ctrnn_prex): pre_x[t,b,j] = x[t,b,:]·W_in[j,:] + b_in[j] + b_hh[j]
//    + noise[t,j]  -- no serial dependence, fully parallel, written to d_ws.
//  Kernel 2 (ctrnn_rec): persistent block per batch element, 4-way k-split
//    (1024 threads: thread (q,j) holds W_hh[j, q*64..+64) in 64 VGPRs).
//    #pragma unroll 4 on the LDS dot loop caps hoisted ds_read pressure so the
//    weights stay in ARCH VGPRs (R2 lesson: full unroll -> peak pressure 300+
//    -> compiler moved weights to AGPRs -> v_accvgpr_read per FMA, 2x VALU).
//  4 waves/SIMD (vs R2's 2) doubles latency hiding on the LDS broadcast reads.

#define T_STEPS 512
#define BATCH   256
#define INSZ    64
#define HID     256
#define ALPHA_F 0.2f
#define OMA_F   0.8f

// ---------------------------------------------------------------------------
// Kernel 1: pre_x = x @ W_in^T + b_in + b_hh + noise  (t-broadcast noise)
// 256 blocks x 1024 threads. Thread (g, j): g = pair-group 0..3, j = hidden
// unit. W_in[j,:] register-resident (64 VGPRs). x rows staged in LDS
// (double-buffered), broadcast-read. 512 (t,b) pairs per block.
// ---------------------------------------------------------------------------
__global__ __launch_bounds__(1024, 4)
void ctrnn_prex(const float* __restrict__ x,      // [T, B, I]
                const float* __restrict__ noise,  // [T, H]
                const float* __restrict__ W_in,   // [H, I]
                const float* __restrict__ b_in,   // [H]
                const float* __restrict__ b_hh,   // [H]
                float* __restrict__ prex)         // [T, B, H] (ws)
{
    const int tid = threadIdx.x;
    const int j   = tid & (HID - 1);
    const int g   = tid >> 8;            // 0..3, wave-uniform

    __shared__ __align__(16) float xs[2][4][INSZ];

    float win[INSZ];
#pragma unroll
    for (int k = 0; k < INSZ; k += 4) {
        float4 v = *reinterpret_cast<const float4*>(&W_in[j * INSZ + k]);
        win[k] = v.x; win[k+1] = v.y; win[k+2] = v.z; win[k+3] = v.w;
    }
    const float bias = b_in[j] + b_hh[j];

    const int base = blockIdx.x * 512;   // 512 pairs per block
    // stage pair for i=0: p = base + g
    if (j < INSZ / 4) {
        *reinterpret_cast<float4*>(&xs[0][g][4 * j]) =
            *reinterpret_cast<const float4*>(&x[(size_t)(base + g) * INSZ + 4 * j]);
    }
    __syncthreads();

    int cur = 0;
#pragma unroll 1
    for (int i = 0; i < 128; ++i) {      // group g handles p = base + 4*i + g
        const int p = base + 4 * i + g;
        // stage next pair while computing this one
        if (i + 1 < 128 && j < INSZ / 4) {
            *reinterpret_cast<float4*>(&xs[cur ^ 1][g][4 * j]) =
                *reinterpret_cast<const float4*>(
                    &x[(size_t)(p + 4) * INSZ + 4 * j]);
        }
        const int t = p >> 8;            // p = t*BATCH + b, BATCH=256
        const float nz = noise[t * HID + j];

        float a0 = 0.f, a1 = 0.f, a2 = 0.f, a3 = 0.f;
#pragma unroll 4
        for (int k = 0; k < INSZ; k += 4) {
            float4 xv = *reinterpret_cast<const float4*>(&xs[cur][g][k]);
            a0 = fmaf(win[k],     xv.x, a0);
            a1 = fmaf(win[k + 1], xv.y, a1);
            a2 = fmaf(win[k + 2], xv.z, a2);
            a3 = fmaf(win[k + 3], xv.w, a3);
        }
        prex[(size_t)p * HID + j] = (a0 + a1) + (a2 + a3) + bias + nz;
        __syncthreads();                 // xs[cur^1] published, xs[cur] done
        cur ^= 1;
    }
}

// ---------------------------------------------------------------------------
// Kernel 2: the recurrence. 256 blocks (1/batch) x 1024 threads.
// Thread (q, j): q = k-quarter, j = hidden unit. whh[64] in arch VGPRs.
// h double-buffered in LDS (broadcast reads); q=1..3 publish partials via
// pbuf; q=0 combines, applies leak+relu, streams out, republishes h.
// ---------------------------------------------------------------------------
__global__ __launch_bounds__(1024, 4)
void ctrnn_rec(const float* __restrict__ hidden,  // [B, H]
               const float* __restrict__ prex,    // [T, B, H] (ws)
               const float* __restrict__ W_hh,    // [H, H]
               float* __restrict__ out)           // [T,B,H] ++ [B,H]
{
    const int tid = threadIdx.x;
    const int j   = tid & (HID - 1);
    const int q   = tid >> 8;            // 0..3, wave-uniform
    const int b   = blockIdx.x;

    __shared__ __align__(16) float hbuf[2][HID];
    __shared__ __align__(16) float pbuf[3][HID];

    float whh[64];
    const float* wrow = &W_hh[j * HID + q * 64];
#pragma unroll
    for (int k = 0; k < 64; k += 4) {
        float4 v = *reinterpret_cast<const float4*>(&wrow[k]);
        whh[k] = v.x; whh[k+1] = v.y; whh[k+2] = v.z; whh[k+3] = v.w;
    }

    float hj = 0.f, pcur = 0.f;
    if (q == 0) {
        hj = hidden[b * HID + j];
        hbuf[0][j] = hj;
        pcur = prex[(size_t)b * HID + j];     // t=0 row
    }
    __syncthreads();

    const int hoff = q * 64;
    int cur = 0;
#pragma unroll 1
    for (int t = 0; t < T_STEPS; ++t) {
        // prefetch next step's pre_x while computing this step
        float pnext = 0.f;
        if (q == 0 && t + 1 < T_STEPS) {
            pnext = prex[((size_t)(t + 1) * BATCH + b) * HID + j];
        }

        float a0 = 0.f, a1 = 0.f, a2 = 0.f, a3 = 0.f;
#pragma unroll 4
        for (int k = 0; k < 64; k += 4) {
            float4 hv = *reinterpret_cast<const float4*>(&hbuf[cur][hoff + k]);
            a0 = fmaf(whh[k],     hv.x, a0);
            a1 = fmaf(whh[k + 1], hv.y, a1);
            a2 = fmaf(whh[k + 2], hv.z, a2);
            a3 = fmaf(whh[k + 3], hv.w, a3);
        }
        const float acc = (a0 + a1) + (a2 + a3);

        if (q) pbuf[q - 1][j] = acc;
        __syncthreads();                  // partials visible; hbuf[cur] reads done

        const int nxt = cur ^ 1;
        if (q == 0) {
            const float pre = acc + pbuf[0][j] + pbuf[1][j] + pbuf[2][j] + pcur;
            hj = fmaxf(fmaf(OMA_F, hj, ALPHA_F * pre), 0.f);
            out[((size_t)t * BATCH + b) * HID + j] = hj;   // coalesced 1 KB
            hbuf[nxt][j] = hj;
            pcur = pnext;
        }
        __syncthreads();                  // hbuf[nxt] published
        cur = nxt;
    }

    if (q == 0) {
        out[(size_t)T_STEPS * BATCH * HID + (size_t)b * HID + j] = hj;
    }
}

// ---------------------------------------------------------------------------
// Fallback (ws too small): R2's monolithic kernel, known-good at 567 us.
// ---------------------------------------------------------------------------
__global__ __launch_bounds__(512, 2)
void ctrnn_mono(const float* __restrict__ x, const float* __restrict__ hidden,
                const float* __restrict__ noise, const float* __restrict__ W_in,
                const float* __restrict__ b_in, const float* __restrict__ W_hh,
                const float* __restrict__ b_hh, float* __restrict__ out)
{
    const int tid  = threadIdx.x;
    const int j    = tid & (HID - 1);
    const int half = tid >> 8;
    const int b    = blockIdx.x;

    __shared__ __align__(16) float hbuf[2][HID];
    __shared__ __align__(16) float xbuf[2][INSZ];
    __shared__ __align__(16) float pbuf[HID];

    float whh[128];
    const float* wrow = &W_hh[j * HID + half * 128];
#pragma unroll
    for (int k = 0; k < 128; k += 4) {
        float4 v = *reinterpret_cast<const float4*>(&wrow[k]);
        whh[k] = v.x; whh[k+1] = v.y; whh[k+2] = v.z; whh[k+3] = v.w;
    }
    float win[32];
    const float* wirow = &W_in[j * INSZ + half * 32];
#pragma unroll
    for (int k = 0; k < 32; k += 4) {
        float4 v = *reinterpret_cast<const float4*>(&wirow[k]);
        win[k] = v.x; win[k+1] = v.y; win[k+2] = v.z; win[k+3] = v.w;
    }

    float bias = 0.f, hj = 0.f, noise_j = 0.f;
    if (half == 0) {
        bias = b_in[j] + b_hh[j];
        hj = hidden[b * HID + j];
        hbuf[0][j] = hj;
        noise_j = noise[j];
        if (j < INSZ / 4) {
            *reinterpret_cast<float4*>(&xbuf[0][4 * j]) =
                *reinterpret_cast<const float4*>(&x[(size_t)b * INSZ + 4 * j]);
        }
    }
    __syncthreads();

    const int hoff = half * 128;
    const int ioff = half * 32;
    int cur = 0;
#pragma unroll 1
    for (int t = 0; t < T_STEPS; ++t) {
        float4 xnext = make_float4(0.f, 0.f, 0.f, 0.f);
        float  nnext = 0.f;
        if (half == 1) {
            if (j < INSZ / 4 && t + 1 < T_STEPS) {
                xnext = *reinterpret_cast<const float4*>(
                    &x[((size_t)(t + 1) * BATCH + b) * INSZ + 4 * j]);
            }
        } else if (t + 1 < T_STEPS) {
            nnext = noise[(t + 1) * HID + j];
        }

        float a0 = 0.f, a1 = 0.f, a2 = 0.f, a3 = 0.f;
#pragma unroll 4
        for (int k = 0; k < 128; k += 4) {
            float4 hv = *reinterpret_cast<const float4*>(&hbuf[cur][hoff + k]);
            a0 = fmaf(whh[k],     hv.x, a0);
            a1 = fmaf(whh[k + 1], hv.y, a1);
            a2 = fmaf(whh[k + 2], hv.z, a2);
            a3 = fmaf(whh[k + 3], hv.w, a3);
        }
#pragma unroll 4
        for (int k = 0; k < 32; k += 4) {
            float4 xv = *reinterpret_cast<const float4*>(&xbuf[cur][ioff + k]);
            a0 = fmaf(win[k],     xv.x, a0);
            a1 = fmaf(win[k + 1], xv.y, a1);
            a2 = fmaf(win[k + 2], xv.z, a2);
            a3 = fmaf(win[k + 3], xv.w, a3);
        }
        const float acc = (a0 + a1) + (a2 + a3);

        if (half == 1) pbuf[j] = acc;
        __syncthreads();

        const int nxt = cur ^ 1;
        if (half == 0) {
            const float pre = acc + pbuf[j] + bias + noise_j;
            hj = fmaxf(fmaf(OMA_F, hj, ALPHA_F * pre), 0.f);
            out[((size_t)t * BATCH + b) * HID + j] = hj;
            hbuf[nxt][j] = hj;
            noise_j = nnext;
        } else if (j < INSZ / 4 && t + 1 < T_STEPS) {
            *reinterpret_cast<float4*>(&xbuf[nxt][4 * j]) = xnext;
        }
        __syncthreads();
        cur = nxt;
    }

    if (half == 0) {
        out[(size_t)T_STEPS * BATCH * HID + (size_t)b * HID + j] = hj;
    }
}

extern "C" void kernel_launch(void* const* d_in, const int* in_sizes, int n_in,
                              void* d_out, int out_size, void* d_ws, size_t ws_size,
                              hipStream_t stream) {
    const float* x      = (const float*)d_in[0];
    const float* hidden = (const float*)d_in[1];
    const float* noise  = (const float*)d_in[2];
    const float* W_in   = (const float*)d_in[3];
    const float* b_in   = (const float*)d_in[4];
    const float* W_hh   = (const float*)d_in[5];
    const float* b_hh   = (const float*)d_in[6];
    float* out = (float*)d_out;

    const size_t prex_bytes = (size_t)T_STEPS * BATCH * HID * sizeof(float);
    if (ws_size >= prex_bytes) {
        float* prex = (float*)d_ws;
        hipLaunchKernelGGL(ctrnn_prex, dim3(BATCH), dim3(1024), 0, stream,
                           x, noise, W_in, b_in, b_hh, prex);
        hipLaunchKernelGGL(ctrnn_rec, dim3(BATCH), dim3(1024), 0, stream,
                           hidden, prex, W_hh, out);
    } else {
        hipLaunchKernelGGL(ctrnn_mono, dim3(BATCH), dim3(512), 0, stream,
                           x, hidden, noise, W_in, b_in, W_hh, b_hh, out);
    }
}

// Round 4
// 611.264 us; speedup vs baseline: 9.4847x; 9.4847x over previous
//
#include <hip/hip_runtime.h>

// CTRNN: T=512, B=256, I=64, H=256.
//   pre = x_t @ W_in^T + b_in + h @ W_hh^T + b_hh + noise_t
//   h   = max(0.8*h + 0.2*pre, 0)
//
// R3 lesson (FETCH_SIZE 16.8 GB, VGPR=32): partially-unrolled loops index
// private arrays with runtime k -> compiler demotes them to SCRATCH. All
// private-array loops below are FULLY unrolled (compile-time indices only).
// R2 lesson (VGPR=104, VALUBusy 2x FMA count): >128 weight floats/thread
// overflows into AGPRs -> v_accvgpr_read per FMA. Cap weights at 64/thread.
//
// Structure:
//  K1 ctrnn_prex: pre_x[t,b,j] = x[t,b,:]&W_in[j,:] + b_in + b_hh + noise[t,j]
//     (no serial dep; 512 blocks x 512 threads; W_in rows in regs).
//  K2 ctrnn_rec: 256 blocks (1/batch) x 1024 threads (4 waves/SIMD).
//     Thread (g=tid>>6, jj=tid&63): rows {jj+64m, m=0..3}, k in [16g,16g+16).
//     4x row-reuse: read h-chunk once (4 broadcast ds_read_b128), 64 FMAs.
//     Partials -> pbuf[16][256] (conflict-free); tid<256 reduce + update.
//     pre_x prefetched 2 steps deep to cover HBM latency.

#define T_STEPS 512
#define BATCH   256
#define INSZ    64
#define HID     256
#define ALPHA_F 0.2f
#define OMA_F   0.8f

// ---------------------------------------------------------------------------
// Kernel 1: pre_x = x @ W_in^T + b_in + b_hh + noise(t)
// 512 blocks x 512 threads: thread (g=tid>>8, j=tid&255); 128 iters x 2 pairs.
// ---------------------------------------------------------------------------
__global__ __launch_bounds__(512, 2)
void ctrnn_prex(const float* __restrict__ x,      // [T, B, I]
                const float* __restrict__ noise,  // [T, H]
                const float* __restrict__ W_in,   // [H, I]
                const float* __restrict__ b_in,   // [H]
                const float* __restrict__ b_hh,   // [H]
                float* __restrict__ prex)         // [T, B, H] (ws)
{
    const int tid = threadIdx.x;
    const int j   = tid & (HID - 1);
    const int g   = tid >> 8;            // 0..1, wave-uniform

    __shared__ __align__(16) float xs[2][2][INSZ];

    float win[INSZ];
#pragma unroll
    for (int k = 0; k < INSZ; k += 4) {
        float4 v = *reinterpret_cast<const float4*>(&W_in[j * INSZ + k]);
        win[k] = v.x; win[k+1] = v.y; win[k+2] = v.z; win[k+3] = v.w;
    }
    const float bias = b_in[j] + b_hh[j];

    const int base = blockIdx.x * 256;   // 256 pairs per block
    if (j < INSZ / 4) {
        *reinterpret_cast<float4*>(&xs[0][g][4 * j]) =
            *reinterpret_cast<const float4*>(&x[(size_t)(base + g) * INSZ + 4 * j]);
    }
    __syncthreads();

    int cur = 0;
#pragma unroll 1
    for (int i = 0; i < 128; ++i) {      // group g handles p = base + 2*i + g
        const int p = base + 2 * i + g;
        if (i + 1 < 128 && j < INSZ / 4) {
            *reinterpret_cast<float4*>(&xs[cur ^ 1][g][4 * j]) =
                *reinterpret_cast<const float4*>(
                    &x[(size_t)(p + 2) * INSZ + 4 * j]);
        }
        const int t = p >> 8;            // p = t*BATCH + b
        const float nz = noise[t * HID + j];

        float a0 = 0.f, a1 = 0.f, a2 = 0.f, a3 = 0.f;
#pragma unroll
        for (int k = 0; k < INSZ; k += 4) {   // FULL unroll: win[] const-indexed
            float4 xv = *reinterpret_cast<const float4*>(&xs[cur][g][k]);
            a0 = fmaf(win[k],     xv.x, a0);
            a1 = fmaf(win[k + 1], xv.y, a1);
            a2 = fmaf(win[k + 2], xv.z, a2);
            a3 = fmaf(win[k + 3], xv.w, a3);
        }
        prex[(size_t)p * HID + j] = (a0 + a1) + (a2 + a3) + bias + nz;
        __syncthreads();
        cur ^= 1;
    }
}

// ---------------------------------------------------------------------------
// Kernel 2: the recurrence. 256 blocks x 1024 threads, 4 waves/SIMD.
// ---------------------------------------------------------------------------
__global__ __launch_bounds__(1024, 4)
void ctrnn_rec(const float* __restrict__ hidden,  // [B, H]
               const float* __restrict__ prex,    // [T, B, H] (ws)
               const float* __restrict__ W_hh,    // [H, H]
               float* __restrict__ out)           // [T,B,H] ++ [B,H]
{
    const int tid = threadIdx.x;
    const int jj  = tid & 63;            // lane  -> row offset
    const int g   = tid >> 6;            // 0..15 -> k-chunk, wave-uniform
    const int b   = blockIdx.x;

    __shared__ __align__(16) float hbuf[2][HID];
    __shared__ __align__(16) float pbuf[16][HID];

    // Weights: 4 rows x 16 k = 64 floats, FULLY const-indexed -> arch VGPRs.
    float w[4][16];
#pragma unroll
    for (int m = 0; m < 4; ++m) {
        const float* wrow = &W_hh[(jj + 64 * m) * HID + 16 * g];
#pragma unroll
        for (int c = 0; c < 4; ++c) {
            float4 v = *reinterpret_cast<const float4*>(&wrow[4 * c]);
            w[m][4*c]   = v.x; w[m][4*c+1] = v.y;
            w[m][4*c+2] = v.z; w[m][4*c+3] = v.w;
        }
    }

    float hj = 0.f, pcur = 0.f, pn1 = 0.f;
    if (tid < HID) {                     // reduce/update threads: row r = tid
        hj = hidden[b * HID + tid];
        hbuf[0][tid] = hj;
        pcur = prex[(size_t)b * HID + tid];                       // t=0
        pn1  = prex[((size_t)1 * BATCH + b) * HID + tid];         // t=1
    }
    __syncthreads();

    const int koff = 16 * g;
    int cur = 0;
#pragma unroll 1
    for (int t = 0; t < T_STEPS; ++t) {
        // 2-deep prefetch: issue load for t+2 at the top (max latency cover).
        float pn2 = 0.f;
        if (tid < HID && t + 2 < T_STEPS) {
            pn2 = prex[((size_t)(t + 2) * BATCH + b) * HID + tid];
        }

        // h-chunk read ONCE (4 broadcast b128), reused across 4 rows.
        float4 h0 = *reinterpret_cast<const float4*>(&hbuf[cur][koff]);
        float4 h1 = *reinterpret_cast<const float4*>(&hbuf[cur][koff + 4]);
        float4 h2 = *reinterpret_cast<const float4*>(&hbuf[cur][koff + 8]);
        float4 h3 = *reinterpret_cast<const float4*>(&hbuf[cur][koff + 12]);

        float acc[4];
#pragma unroll
        for (int m = 0; m < 4; ++m) {
            float a = 0.f, bq = 0.f;
            a  = fmaf(w[m][0],  h0.x, a);  bq = fmaf(w[m][1],  h0.y, bq);
            a  = fmaf(w[m][2],  h0.z, a);  bq = fmaf(w[m][3],  h0.w, bq);
            a  = fmaf(w[m][4],  h1.x, a);  bq = fmaf(w[m][5],  h1.y, bq);
            a  = fmaf(w[m][6],  h1.z, a);  bq = fmaf(w[m][7],  h1.w, bq);
            a  = fmaf(w[m][8],  h2.x, a);  bq = fmaf(w[m][9],  h2.y, bq);
            a  = fmaf(w[m][10], h2.z, a);  bq = fmaf(w[m][11], h2.w, bq);
            a  = fmaf(w[m][12], h3.x, a);  bq = fmaf(w[m][13], h3.y, bq);
            a  = fmaf(w[m][14], h3.z, a);  bq = fmaf(w[m][15], h3.w, bq);
            acc[m] = a + bq;
        }
        // Conflict-free partial writes (lanes -> consecutive rows).
        pbuf[g][jj]       = acc[0];
        pbuf[g][jj + 64]  = acc[1];
        pbuf[g][jj + 128] = acc[2];
        pbuf[g][jj + 192] = acc[3];
        __syncthreads();                 // partials visible; hbuf[cur] done

        const int nxt = cur ^ 1;
        if (tid < HID) {
            float s = pcur;
#pragma unroll
            for (int gg = 0; gg < 16; ++gg) s += pbuf[gg][tid];
            hj = fmaxf(fmaf(OMA_F, hj, ALPHA_F * s), 0.f);
            out[((size_t)t * BATCH + b) * HID + tid] = hj;   // coalesced 1 KB
            hbuf[nxt][tid] = hj;
            pcur = pn1; pn1 = pn2;
        }
        __syncthreads();                 // hbuf[nxt] published
        cur = nxt;
    }

    if (tid < HID) {
        out[(size_t)T_STEPS * BATCH * HID + (size_t)b * HID + tid] = hj;
    }
}

// ---------------------------------------------------------------------------
// Fallback (ws too small): R2's monolithic kernel (full unroll, known 567 us).
// ---------------------------------------------------------------------------
__global__ __launch_bounds__(512, 2)
void ctrnn_mono(const float* __restrict__ x, const float* __restrict__ hidden,
                const float* __restrict__ noise, const float* __restrict__ W_in,
                const float* __restrict__ b_in, const float* __restrict__ W_hh,
                const float* __restrict__ b_hh, float* __restrict__ out)
{
    const int tid  = threadIdx.x;
    const int j    = tid & (HID - 1);
    const int half = tid >> 8;
    const int b    = blockIdx.x;

    __shared__ __align__(16) float hbuf[2][HID];
    __shared__ __align__(16) float xbuf[2][INSZ];
    __shared__ __align__(16) float pbuf[HID];

    float whh[128];
    const float* wrow = &W_hh[j * HID + half * 128];
#pragma unroll
    for (int k = 0; k < 128; k += 4) {
        float4 v = *reinterpret_cast<const float4*>(&wrow[k]);
        whh[k] = v.x; whh[k+1] = v.y; whh[k+2] = v.z; whh[k+3] = v.w;
    }
    float win[32];
    const float* wirow = &W_in[j * INSZ + half * 32];
#pragma unroll
    for (int k = 0; k < 32; k += 4) {
        float4 v = *reinterpret_cast<const float4*>(&wirow[k]);
        win[k] = v.x; win[k+1] = v.y; win[k+2] = v.z; win[k+3] = v.w;
    }

    float bias = 0.f, hj = 0.f, noise_j = 0.f;
    if (half == 0) {
        bias = b_in[j] + b_hh[j];
        hj = hidden[b * HID + j];
        hbuf[0][j] = hj;
        noise_j = noise[j];
        if (j < INSZ / 4) {
            *reinterpret_cast<float4*>(&xbuf[0][4 * j]) =
                *reinterpret_cast<const float4*>(&x[(size_t)b * INSZ + 4 * j]);
        }
    }
    __syncthreads();

    const int hoff = half * 128;
    const int ioff = half * 32;
    int cur = 0;
#pragma unroll 1
    for (int t = 0; t < T_STEPS; ++t) {
        float4 xnext = make_float4(0.f, 0.f, 0.f, 0.f);
        float  nnext = 0.f;
        if (half == 1) {
            if (j < INSZ / 4 && t + 1 < T_STEPS) {
                xnext = *reinterpret_cast<const float4*>(
                    &x[((size_t)(t + 1) * BATCH + b) * INSZ + 4 * j]);
            }
        } else if (t + 1 < T_STEPS) {
            nnext = noise[(t + 1) * HID + j];
        }

        float a0 = 0.f, a1 = 0.f, a2 = 0.f, a3 = 0.f;
#pragma unroll
        for (int k = 0; k < 128; k += 4) {   // FULL unroll
            float4 hv = *reinterpret_cast<const float4*>(&hbuf[cur][hoff + k]);
            a0 = fmaf(whh[k],     hv.x, a0);
            a1 = fmaf(whh[k + 1], hv.y, a1);
            a2 = fmaf(whh[k + 2], hv.z, a2);
            a3 = fmaf(whh[k + 3], hv.w, a3);
        }
#pragma unroll
        for (int k = 0; k < 32; k += 4) {    // FULL unroll
            float4 xv = *reinterpret_cast<const float4*>(&xbuf[cur][ioff + k]);
            a0 = fmaf(win[k],     xv.x, a0);
            a1 = fmaf(win[k + 1], xv.y, a1);
            a2 = fmaf(win[k + 2], xv.z, a2);
            a3 = fmaf(win[k + 3], xv.w, a3);
        }
        const float acc = (a0 + a1) + (a2 + a3);

        if (half == 1) pbuf[j] = acc;
        __syncthreads();

        const int nxt = cur ^ 1;
        if (half == 0) {
            const float pre = acc + pbuf[j] + bias + noise_j;
            hj = fmaxf(fmaf(OMA_F, hj, ALPHA_F * pre), 0.f);
            out[((size_t)t * BATCH + b) * HID + j] = hj;
            hbuf[nxt][j] = hj;
            noise_j = nnext;
        } else if (j < INSZ / 4 && t + 1 < T_STEPS) {
            *reinterpret_cast<float4*>(&xbuf[nxt][4 * j]) = xnext;
        }
        __syncthreads();
        cur = nxt;
    }

    if (half == 0) {
        out[(size_t)T_STEPS * BATCH * HID + (size_t)b * HID + j] = hj;
    }
}

extern "C" void kernel_launch(void* const* d_in, const int* in_sizes, int n_in,
                              void* d_out, int out_size, void* d_ws, size_t ws_size,
                              hipStream_t stream) {
    const float* x      = (const float*)d_in[0];
    const float* hidden = (const float*)d_in[1];
    const float* noise  = (const float*)d_in[2];
    const float* W_in   = (const float*)d_in[3];
    const float* b_in   = (const float*)d_in[4];
    const float* W_hh   = (const float*)d_in[5];
    const float* b_hh   = (const float*)d_in[6];
    float* out = (float*)d_out;

    const size_t prex_bytes = (size_t)T_STEPS * BATCH * HID * sizeof(float);
    if (ws_size >= prex_bytes) {
        float* prex = (float*)d_ws;
        hipLaunchKernelGGL(ctrnn_prex, dim3(512), dim3(512), 0, stream,
                           x, noise, W_in, b_in, b_hh, prex);
        hipLaunchKernelGGL(ctrnn_rec, dim3(BATCH), dim3(1024), 0, stream,
                           hidden, prex, W_hh, out);
    } else {
        hipLaunchKernelGGL(ctrnn_mono, dim3(BATCH), dim3(512), 0, stream,
                           x, hidden, noise, W_in, b_in, W_hh, b_hh, out);
    }
}